// Round 1
// baseline (930.108 us; speedup 1.0000x reference)
//
#include <hip/hip_runtime.h>
#include <hip/hip_bf16.h>

#define BATCH 8
#define NN    2048
#define FF    256
#define LL    16

// ---------------------------------------------------------------------------
// Kernel A: per-row projection z = x @ proj_w^T + proj_b  (L=16),
// then pi = sigmoid(w2 @ relu(w1 @ z + b1) + b2).  One wave per row.
// ---------------------------------------------------------------------------
__global__ __launch_bounds__(64) void proj_pi_kernel(
    const float* __restrict__ x,
    const float* __restrict__ proj_w, const float* __restrict__ proj_b,
    const float* __restrict__ pi_w1,  const float* __restrict__ pi_b1,
    const float* __restrict__ pi_w2,  const float* __restrict__ pi_b2,
    float* __restrict__ zbuf,   // [B*N, 16]
    float* __restrict__ pibuf)  // [B*N]
{
    const int n    = blockIdx.x;       // 0 .. B*N-1
    const int lane = threadIdx.x;      // 0 .. 63

    const float* xr = x + (size_t)n * FF;
    float xv[4];
#pragma unroll
    for (int k = 0; k < 4; ++k) xv[k] = xr[lane + 64 * k];

    float z[LL];
#pragma unroll
    for (int l = 0; l < LL; ++l) {
        const float* wr = proj_w + l * FF;
        float p = 0.f;
#pragma unroll
        for (int k = 0; k < 4; ++k) p = fmaf(xv[k], wr[lane + 64 * k], p);
#pragma unroll
        for (int s = 32; s >= 1; s >>= 1) p += __shfl_xor(p, s, 64);
        z[l] = p + proj_b[l];
        if (lane == 0) zbuf[(size_t)n * LL + l] = z[l];
    }

    // MLP: h = relu(z @ pi_w1^T + pi_b1) [256], pi = sigmoid(h . pi_w2 + b2)
    float psum = 0.f;
#pragma unroll
    for (int k = 0; k < 4; ++k) {
        const int f = lane + 64 * k;
        const float* w1 = pi_w1 + f * LL;
        float h = pi_b1[f];
#pragma unroll
        for (int l = 0; l < LL; ++l) h = fmaf(z[l], w1[l], h);
        h = fmaxf(h, 0.f);
        psum = fmaf(h, pi_w2[f], psum);
    }
#pragma unroll
    for (int s = 32; s >= 1; s >>= 1) psum += __shfl_xor(psum, s, 64);
    if (lane == 0) {
        const float t = psum + pi_b2[0];
        pibuf[n] = 1.f / (1.f + __expf(-t));
    }
}

// ---------------------------------------------------------------------------
// Kernel Q: q[n] = sum_m exp(-|z_n - z_m|^2); writes c[n] = pi[n] / q[n].
// Block: 256 threads = 64 rows x 4 m-slots.  z chunks staged in LDS.
// Grid: B * (N/64) = 256 blocks, batch = blockIdx % 8 (XCD locality).
// ---------------------------------------------------------------------------
__global__ __launch_bounds__(256) void qc_kernel(
    const float* __restrict__ zbuf,
    const float* __restrict__ pibuf,
    float* __restrict__ cbuf)  // [B*N]
{
    const int bid  = blockIdx.x;
    const int b    = bid & 7;
    const int tile = bid >> 3;           // 0..31
    const int n0   = tile * 64;
    const int tid  = threadIdx.x;
    const int r    = tid >> 2;           // 0..63 local row
    const int ms   = tid & 3;            // m slot

    const float* zb = zbuf + (size_t)b * NN * LL;
    const int n = n0 + r;

    float zr[LL];
#pragma unroll
    for (int l = 0; l < LL; ++l) zr[l] = zb[(size_t)n * LL + l];

    __shared__ float zsh[512 * LL];      // 32 KB
    float qacc = 0.f;

    for (int c0 = 0; c0 < NN; c0 += 512) {
        __syncthreads();
        const float4* src = (const float4*)(zb + (size_t)c0 * LL);
        float4* dst = (float4*)zsh;
        for (int i = tid; i < 512 * LL / 4; i += 256) dst[i] = src[i];
        __syncthreads();

        for (int mm = ms; mm < 512; mm += 4) {
            const float* zm = &zsh[mm * LL];
            float d2 = 0.f;
#pragma unroll
            for (int l = 0; l < LL; ++l) {
                const float d = zr[l] - zm[l];
                d2 = fmaf(d, d, d2);
            }
            qacc += __expf(-d2);
        }
    }
    qacc += __shfl_xor(qacc, 1, 64);
    qacc += __shfl_xor(qacc, 2, 64);
    if (ms == 0) {
        const size_t gi = (size_t)b * NN + n;
        cbuf[gi] = pibuf[gi] / qacc;
    }
}

// ---------------------------------------------------------------------------
// Kernel M: out[n,f] = (1-dt)*x[n,f] + 4*dt/(rowsum[n]+1e-5) *
//                      sum_m exp(-|z_n-z_m|^2)*c[m]*x[m,f]
// Block: 256 threads, 32 rows x 256 cols, m chunked by 64.
// Phase 1: w tile -> LDS (stride 65).  Phase 2: 4x8 register blocking.
// Grid: B * (N/32) = 512, batch = blockIdx % 8 (XCD locality).
// ---------------------------------------------------------------------------
__global__ __launch_bounds__(256) void main_kernel(
    const float* __restrict__ x,
    const float* __restrict__ zbuf,
    const float* __restrict__ cbuf,
    const float* __restrict__ dtp,
    float* __restrict__ out)
{
    const int bid  = blockIdx.x;
    const int b    = bid & 7;
    const int tile = bid >> 3;          // 0..63
    const int n0   = tile * 32;
    const int tid  = threadIdx.x;

    const float* xb = x    + (size_t)b * NN * FF;
    const float* zb = zbuf + (size_t)b * NN * LL;
    const float* cb = cbuf + (size_t)b * NN;
    float*       ob = out  + (size_t)b * NN * FF;

    __shared__ float wsh[32 * 65];      // padded: phase-2 reads conflict-free

    // phase-1 role: thread computes 8 w entries for one row
    const int p1r = tid >> 3;           // 0..31
    const int p1k = tid & 7;            // 0..7
    float zr[LL];
    {
        const float* zp = zb + (size_t)(n0 + p1r) * LL;
#pragma unroll
        for (int l = 0; l < LL; ++l) zr[l] = zp[l];
    }

    // phase-2 role: 4 rows x 8 cols per thread
    const int fo = tid & 31;            // 0..31
    const int rg = tid >> 5;            // 0..7
    const int f0 = fo * 8;

    float acc[4][8];
    float rsum[4];
#pragma unroll
    for (int i = 0; i < 4; ++i) {
        rsum[i] = 0.f;
#pragma unroll
        for (int j = 0; j < 8; ++j) acc[i][j] = 0.f;
    }

    for (int m0 = 0; m0 < NN; m0 += 64) {
        __syncthreads();
        // ---- phase 1: w[r][mm] = exp(-d2(n0+r, m0+mm)) * c[m0+mm]
#pragma unroll
        for (int j = 0; j < 8; ++j) {
            const int mm = p1k * 8 + j;
            const int m  = m0 + mm;
            const float* zm = zb + (size_t)m * LL;
            float d2 = 0.f;
#pragma unroll
            for (int l = 0; l < LL; ++l) {
                const float d = zr[l] - zm[l];
                d2 = fmaf(d, d, d2);
            }
            wsh[p1r * 65 + mm] = __expf(-d2) * cb[m];
        }
        __syncthreads();
        // ---- phase 2: acc += w * x
#pragma unroll 4
        for (int mm = 0; mm < 64; ++mm) {
            const int m = m0 + mm;
            const float4 xa = *(const float4*)(xb + (size_t)m * FF + f0);
            const float4 xc = *(const float4*)(xb + (size_t)m * FF + f0 + 4);
#pragma unroll
            for (int i = 0; i < 4; ++i) {
                const float w = wsh[(rg * 4 + i) * 65 + mm];
                rsum[i] += w;
                acc[i][0] = fmaf(w, xa.x, acc[i][0]);
                acc[i][1] = fmaf(w, xa.y, acc[i][1]);
                acc[i][2] = fmaf(w, xa.z, acc[i][2]);
                acc[i][3] = fmaf(w, xa.w, acc[i][3]);
                acc[i][4] = fmaf(w, xc.x, acc[i][4]);
                acc[i][5] = fmaf(w, xc.y, acc[i][5]);
                acc[i][6] = fmaf(w, xc.z, acc[i][6]);
                acc[i][7] = fmaf(w, xc.w, acc[i][7]);
            }
        }
    }

    const float dtv = dtp[0];
#pragma unroll
    for (int i = 0; i < 4; ++i) {
        const int n = n0 + rg * 4 + i;
        const float inv = 4.0f * dtv / (rsum[i] + 1e-5f);
        const float* xr = xb + (size_t)n * FF + f0;
        float*       orow = ob + (size_t)n * FF + f0;
#pragma unroll
        for (int j = 0; j < 8; ++j)
            orow[j] = (1.f - dtv) * xr[j] + inv * acc[i][j];
    }
}

// ---------------------------------------------------------------------------
extern "C" void kernel_launch(void* const* d_in, const int* in_sizes, int n_in,
                              void* d_out, int out_size, void* d_ws, size_t ws_size,
                              hipStream_t stream) {
    const float* x      = (const float*)d_in[0];
    const float* proj_w = (const float*)d_in[1];
    const float* proj_b = (const float*)d_in[2];
    const float* pi_w1  = (const float*)d_in[3];
    const float* pi_b1  = (const float*)d_in[4];
    const float* pi_w2  = (const float*)d_in[5];
    const float* pi_b2  = (const float*)d_in[6];
    const float* dtp    = (const float*)d_in[7];
    float* out = (float*)d_out;

    // workspace layout
    float* zbuf  = (float*)d_ws;                                  // B*N*16
    float* pibuf = zbuf + (size_t)BATCH * NN * LL;                // B*N
    float* cbuf  = pibuf + (size_t)BATCH * NN;                    // B*N

    proj_pi_kernel<<<dim3(BATCH * NN), dim3(64), 0, stream>>>(
        x, proj_w, proj_b, pi_w1, pi_b1, pi_w2, pi_b2, zbuf, pibuf);

    qc_kernel<<<dim3(BATCH * (NN / 64)), dim3(256), 0, stream>>>(
        zbuf, pibuf, cbuf);

    main_kernel<<<dim3(BATCH * (NN / 32)), dim3(256), 0, stream>>>(
        x, zbuf, cbuf, dtp, out);
}

// Round 2
// 225.048 us; speedup vs baseline: 4.1329x; 4.1329x over previous
//
#include <hip/hip_runtime.h>
#include <hip/hip_bf16.h>

#define BATCH 8
#define NN    2048
#define FF    256
#define LL    16

typedef float f32x4 __attribute__((ext_vector_type(4)));
typedef short s16x8 __attribute__((ext_vector_type(8)));

__device__ __forceinline__ unsigned short f2bf(float f) {
    return __builtin_bit_cast(unsigned short, __float2bfloat16(f));
}

typedef const __attribute__((address_space(1))) unsigned int glb_uint;
typedef __attribute__((address_space(3))) unsigned int lds_uint;
__device__ __forceinline__ void gload_lds16(const void* g, void* l) {
    __builtin_amdgcn_global_load_lds((glb_uint*)g, (lds_uint*)l, 16, 0, 0);
}

// ---------------------------------------------------------------------------
// Kernel A: z = proj(x), sq = |z|^2, pi = sigmoid(MLP(z)).  One wave per row.
// ---------------------------------------------------------------------------
__global__ __launch_bounds__(64) void proj_pi_kernel(
    const float* __restrict__ x,
    const float* __restrict__ proj_w, const float* __restrict__ proj_b,
    const float* __restrict__ pi_w1,  const float* __restrict__ pi_b1,
    const float* __restrict__ pi_w2,  const float* __restrict__ pi_b2,
    float* __restrict__ zbuf,   // [B*N, 16]
    float* __restrict__ sqbuf,  // [B*N]
    float* __restrict__ pibuf)  // [B*N]
{
    const int n    = blockIdx.x;
    const int lane = threadIdx.x;

    const float* xr = x + (size_t)n * FF;
    float xv[4];
#pragma unroll
    for (int k = 0; k < 4; ++k) xv[k] = xr[lane + 64 * k];

    float z[LL];
#pragma unroll
    for (int l = 0; l < LL; ++l) {
        const float* wr = proj_w + l * FF;
        float p = 0.f;
#pragma unroll
        for (int k = 0; k < 4; ++k) p = fmaf(xv[k], wr[lane + 64 * k], p);
#pragma unroll
        for (int s = 32; s >= 1; s >>= 1) p += __shfl_xor(p, s, 64);
        z[l] = p + proj_b[l];
        if (lane == 0) zbuf[(size_t)n * LL + l] = z[l];
    }
    if (lane == 0) {
        float sq = 0.f;
#pragma unroll
        for (int l = 0; l < LL; ++l) sq = fmaf(z[l], z[l], sq);
        sqbuf[n] = sq;
    }

    float psum = 0.f;
#pragma unroll
    for (int k = 0; k < 4; ++k) {
        const int f = lane + 64 * k;
        const float* w1 = pi_w1 + f * LL;
        float h = pi_b1[f];
#pragma unroll
        for (int l = 0; l < LL; ++l) h = fmaf(z[l], w1[l], h);
        h = fmaxf(h, 0.f);
        psum = fmaf(h, pi_w2[f], psum);
    }
#pragma unroll
    for (int s = 32; s >= 1; s >>= 1) psum += __shfl_xor(psum, s, 64);
    if (lane == 0) {
        const float t = psum + pi_b2[0];
        pibuf[n] = 1.f / (1.f + __expf(-t));
    }
}

// ---------------------------------------------------------------------------
// Kernel T: x [B,N,F] f32 -> xT [B,F,N] bf16 via 64x64 LDS tile.
// Grid: 8 * 32 * 4 = 1024 blocks, 256 threads.
// ---------------------------------------------------------------------------
__global__ __launch_bounds__(256) void transpose_bf16_kernel(
    const float* __restrict__ x, unsigned short* __restrict__ xT)
{
    const int bid = blockIdx.x;
    const int b    = bid & 7;
    const int rest = bid >> 3;       // 0..127
    const int nt   = rest & 31;      // n tile
    const int ft   = rest >> 5;      // 0..3
    const int n0 = nt * 64, f0 = ft * 64;

    const float* xb = x + (size_t)b * NN * FF;
    unsigned short* xTb = xT + (size_t)b * FF * NN;

    __shared__ float lds[64 * 68];   // pad 68 keeps float4 alignment + bank spread
    const int t = threadIdx.x;
    const int r = t >> 4, c = t & 15;

#pragma unroll
    for (int p = 0; p < 4; ++p) {
        const int rr = p * 16 + r;   // local n
        const float4 v = *(const float4*)(xb + (size_t)(n0 + rr) * FF + f0 + c * 4);
        *(float4*)&lds[rr * 68 + c * 4] = v;
    }
    __syncthreads();
#pragma unroll
    for (int p = 0; p < 4; ++p) {
        const int ff = p * 16 + r;   // local f
        ushort4 o;
        o.x = f2bf(lds[(c * 4 + 0) * 68 + ff]);
        o.y = f2bf(lds[(c * 4 + 1) * 68 + ff]);
        o.z = f2bf(lds[(c * 4 + 2) * 68 + ff]);
        o.w = f2bf(lds[(c * 4 + 3) * 68 + ff]);
        *(ushort4*)(xTb + (size_t)(f0 + ff) * NN + n0 + c * 4) = o;
    }
}

// ---------------------------------------------------------------------------
// Kernel Q: q[n] = sum_m exp(-(sq_n + sq_m - 2 z_n.z_m)); c[n] = pi[n]/q[n].
// 256 threads = 32 rows x 8 slots; m chunked by 256 with LDS staging.
// Grid: 8 * 64 = 512 blocks (2/CU), batch = bid & 7 (XCD L2 locality).
// ---------------------------------------------------------------------------
__global__ __launch_bounds__(256) void qc_kernel(
    const float* __restrict__ zbuf,
    const float* __restrict__ sqbuf,
    const float* __restrict__ pibuf,
    float* __restrict__ cbuf)
{
    const int bid  = blockIdx.x;
    const int b    = bid & 7;
    const int tile = bid >> 3;       // 0..63
    const int t    = threadIdx.x;
    const int row  = t >> 3;         // 0..31
    const int slot = t & 7;
    const int n    = tile * 32 + row;

    const float* zb  = zbuf  + (size_t)b * NN * LL;
    const float* sqb = sqbuf + (size_t)b * NN;

    float zr[LL];
#pragma unroll
    for (int q = 0; q < 4; ++q)
        *(float4*)&zr[q * 4] = *(const float4*)(zb + (size_t)n * LL + q * 4);
    const float sqn = sqb[n];

    __shared__ float zsh[256 * LL];  // 16 KB, quad-swizzled by (m&3)
    __shared__ float sqsh[256];

    float qacc = 0.f;
    for (int c0 = 0; c0 < NN; c0 += 256) {
        __syncthreads();
        const float4* src4 = (const float4*)(zb + (size_t)c0 * LL);
        float4* dst4 = (float4*)zsh;
#pragma unroll
        for (int ii = 0; ii < 4; ++ii) {
            const int fi = ii * 256 + t;       // physical float4 slot
            const int m  = fi >> 2, qp = fi & 3;
            dst4[fi] = src4[m * 4 + (qp ^ (m & 3))];
        }
        sqsh[t] = sqb[c0 + t];  // t<256 == blockDim
        __syncthreads();

        for (int mm = slot; mm < 256; mm += 8) {
            float dot = 0.f;
#pragma unroll
            for (int q = 0; q < 4; ++q) {
                const float4 zm = *(const float4*)&zsh[mm * LL + ((q ^ (mm & 3)) * 4)];
                dot = fmaf(zr[q * 4 + 0], zm.x, dot);
                dot = fmaf(zr[q * 4 + 1], zm.y, dot);
                dot = fmaf(zr[q * 4 + 2], zm.z, dot);
                dot = fmaf(zr[q * 4 + 3], zm.w, dot);
            }
            const float d2 = sqn + sqsh[mm] - 2.f * dot;
            qacc += __expf(-d2);
        }
    }
    qacc += __shfl_xor(qacc, 1, 64);
    qacc += __shfl_xor(qacc, 2, 64);
    qacc += __shfl_xor(qacc, 4, 64);
    if (slot == 0) {
        const size_t gi = (size_t)b * NN + n;
        cbuf[gi] = pibuf[gi] / qacc;
    }
}

// ---------------------------------------------------------------------------
// Kernel M (MFMA): C = xT @ w^T per 32-n tile.
//   out[n,f] = (1-dt)*x[n,f] + 4dt/(rowsum[n]+1e-5) * sum_m w[n,m]*x[m,f]
//   w[n,m] = exp(-(sq_n+sq_m-2 z_n.z_m)) * c[m]
// Block: 256 thr = 4 waves; wave w: f in [64w,64w+64), n in [0,32).
// Per K-chunk (64 m): phase1 f32 w -> bf16 LDS (XOR-swizzled);
// xT chunk staged via global_load_lds (pre-swizzled source, linear dest);
// phase2: 16x mfma_f32_16x16x32_bf16 per wave.
// Grid: 8 * 64 = 512 (2/CU), batch = bid & 7 -> per-XCD L2 locality.
// ---------------------------------------------------------------------------
__global__ __launch_bounds__(256) void main_mfma_kernel(
    const float* __restrict__ x,
    const unsigned short* __restrict__ xT,
    const float* __restrict__ zbuf,
    const float* __restrict__ sqbuf,
    const float* __restrict__ cbuf,
    const float* __restrict__ dtp,
    float* __restrict__ out)
{
    const int bid  = blockIdx.x;
    const int b    = bid & 7;
    const int tile = bid >> 3;       // 0..63
    const int n0   = tile * 32;
    const int t    = threadIdx.x;
    const int wv   = t >> 6, ln = t & 63;

    const float*          xb  = x    + (size_t)b * NN * FF;
    const unsigned short* xTb = xT   + (size_t)b * FF * NN;
    const float*          zb  = zbuf + (size_t)b * NN * LL;
    const float*          sqB = sqbuf + (size_t)b * NN;
    const float*          cB  = cbuf + (size_t)b * NN;
    float*                ob  = out  + (size_t)b * NN * FF;

    __shared__ unsigned short xsh[FF * 64];  // 32 KB [f][m], 16B-chunk XOR swizzle by (f&7)
    __shared__ unsigned short wsh[32 * 64];  //  4 KB [n][m], chunk swizzle by (n&7)
    __shared__ float zsh[64 * LL];           //  4 KB [m][l], quad swizzle by ((m>>3)&3)
    __shared__ float csh[64];
    __shared__ float sqsh[64];
    __shared__ float rs[32];

    // phase-1 identity: 32 rows x 8 m-slots
    const int p1n = t >> 3, p1k = t & 7;
    float zr[LL];
#pragma unroll
    for (int q = 0; q < 4; ++q)
        *(float4*)&zr[q * 4] = *(const float4*)(zb + (size_t)(n0 + p1n) * LL + q * 4);
    const float sqn = sqB[n0 + p1n];
    const float dtv = dtp[0];

    f32x4 acc[4][2];
#pragma unroll
    for (int fi = 0; fi < 4; ++fi)
#pragma unroll
        for (int ni = 0; ni < 2; ++ni)
            acc[fi][ni] = (f32x4){0.f, 0.f, 0.f, 0.f};

    float rsum = 0.f;

    for (int m0 = 0; m0 < NN; m0 += 64) {
        __syncthreads();   // prior phase-2 LDS reads done

        // --- stage c, sq chunks (plain) ---
        if (t < 64)        csh[t]       = cB[m0 + t];
        else if (t < 128)  sqsh[t - 64] = sqB[m0 + t - 64];
        // --- stage z chunk (plain, swizzled write) ---
        {
            const int m = t >> 2, qp = t & 3;
            const int ql = qp ^ ((m >> 3) & 3);
            const float4 v = *(const float4*)(zb + (size_t)(m0 + m) * LL + ql * 4);
            *(float4*)&zsh[m * LL + qp * 4] = v;
        }
        // --- stage xT chunk: 8 issues x 4 waves x 1KB (pre-swizzled source) ---
#pragma unroll
        for (int i = 0; i < 8; ++i) {
            const int f  = i * 32 + (t >> 3);
            const int cp = t & 7;                 // physical 16B chunk
            const int cl = cp ^ (f & 7);          // logical chunk in xT row
            const unsigned short* src = xTb + (size_t)f * NN + m0 + cl * 8;
            gload_lds16(src, (char*)xsh + i * 4096 + wv * 1024);
        }
        __syncthreads();   // all staging complete (vmcnt drain)

        // --- phase 1: w[n][m] f32 -> bf16 into wsh ---
        union { s16x8 v; unsigned short u[8]; } pk;
#pragma unroll
        for (int j = 0; j < 8; ++j) {
            const int m = p1k * 8 + j;
            float dot = 0.f;
#pragma unroll
            for (int q = 0; q < 4; ++q) {
                const float4 zm = *(const float4*)&zsh[m * LL + ((q ^ (p1k & 3)) * 4)];
                dot = fmaf(zr[q * 4 + 0], zm.x, dot);
                dot = fmaf(zr[q * 4 + 1], zm.y, dot);
                dot = fmaf(zr[q * 4 + 2], zm.z, dot);
                dot = fmaf(zr[q * 4 + 3], zm.w, dot);
            }
            const float d2 = sqn + sqsh[m] - 2.f * dot;
            const float wf = __expf(-d2) * csh[m];
            rsum += wf;
            pk.u[j] = f2bf(wf);
        }
        *(s16x8*)((char*)wsh + p1n * 128 + ((p1k ^ (p1n & 7)) * 16)) = pk.v;
        __syncthreads();   // wsh visible

        // --- phase 2: 16 mfma per wave ---
#pragma unroll
        for (int ks = 0; ks < 2; ++ks) {
            s16x8 af[4], bfr[2];
#pragma unroll
            for (int fi = 0; fi < 4; ++fi) {
                const int f  = wv * 64 + fi * 16 + (ln & 15);
                const int cl = ks * 4 + (ln >> 4);
                af[fi] = *(const s16x8*)((const char*)xsh + f * 128 + ((cl ^ (f & 7)) * 16));
            }
#pragma unroll
            for (int ni = 0; ni < 2; ++ni) {
                const int n  = ni * 16 + (ln & 15);
                const int cl = ks * 4 + (ln >> 4);
                bfr[ni] = *(const s16x8*)((const char*)wsh + n * 128 + ((cl ^ (n & 7)) * 16));
            }
#pragma unroll
            for (int fi = 0; fi < 4; ++fi)
#pragma unroll
                for (int ni = 0; ni < 2; ++ni)
                    acc[fi][ni] = __builtin_amdgcn_mfma_f32_16x16x32_bf16(
                        af[fi], bfr[ni], acc[fi][ni], 0, 0, 0);
        }
    }

    // rowsum reduce across the 8 p1k slots (consecutive lanes)
    rsum += __shfl_xor(rsum, 1, 64);
    rsum += __shfl_xor(rsum, 2, 64);
    rsum += __shfl_xor(rsum, 4, 64);
    if (p1k == 0) rs[p1n] = rsum;
    __syncthreads();

    // epilogue: C frag -> out[n][f] (col=lane&15 -> n, row=(lane>>4)*4+reg -> f)
#pragma unroll
    for (int ni = 0; ni < 2; ++ni) {
        const int nl = ni * 16 + (ln & 15);
        const float sc = 4.f * dtv / (rs[nl] + 1e-5f);
        const int ng = n0 + nl;
#pragma unroll
        for (int fi = 0; fi < 4; ++fi) {
            const int fg = wv * 64 + fi * 16 + ((ln >> 4) * 4);
            const float4 xv = *(const float4*)(xb + (size_t)ng * FF + fg);
            float4 o;
            o.x = (1.f - dtv) * xv.x + sc * acc[fi][ni][0];
            o.y = (1.f - dtv) * xv.y + sc * acc[fi][ni][1];
            o.z = (1.f - dtv) * xv.z + sc * acc[fi][ni][2];
            o.w = (1.f - dtv) * xv.w + sc * acc[fi][ni][3];
            *(float4*)(ob + (size_t)ng * FF + fg) = o;
        }
    }
}

// ---------------------------------------------------------------------------
extern "C" void kernel_launch(void* const* d_in, const int* in_sizes, int n_in,
                              void* d_out, int out_size, void* d_ws, size_t ws_size,
                              hipStream_t stream) {
    const float* x      = (const float*)d_in[0];
    const float* proj_w = (const float*)d_in[1];
    const float* proj_b = (const float*)d_in[2];
    const float* pi_w1  = (const float*)d_in[3];
    const float* pi_b1  = (const float*)d_in[4];
    const float* pi_w2  = (const float*)d_in[5];
    const float* pi_b2  = (const float*)d_in[6];
    const float* dtp    = (const float*)d_in[7];
    float* out = (float*)d_out;

    // workspace: xT bf16 8MB | z 1MB | sq 64KB | pi 64KB | c 64KB
    unsigned short* xT = (unsigned short*)d_ws;
    float* zbuf  = (float*)(xT + (size_t)BATCH * FF * NN);
    float* sqbuf = zbuf  + (size_t)BATCH * NN * LL;
    float* pibuf = sqbuf + (size_t)BATCH * NN;
    float* cbuf  = pibuf + (size_t)BATCH * NN;

    proj_pi_kernel<<<dim3(BATCH * NN), dim3(64), 0, stream>>>(
        x, proj_w, proj_b, pi_w1, pi_b1, pi_w2, pi_b2, zbuf, sqbuf, pibuf);

    transpose_bf16_kernel<<<dim3(BATCH * 128), dim3(256), 0, stream>>>(x, xT);

    qc_kernel<<<dim3(BATCH * (NN / 32)), dim3(256), 0, stream>>>(
        zbuf, sqbuf, pibuf, cbuf);

    main_mfma_kernel<<<dim3(BATCH * (NN / 32)), dim3(256), 0, stream>>>(
        x, xT, zbuf, sqbuf, cbuf, dtp, out);
}

// Round 3
// 149.601 us; speedup vs baseline: 6.2172x; 1.5043x over previous
//
#include <hip/hip_runtime.h>
#include <hip/hip_bf16.h>

#define BATCH 8
#define NN    2048
#define FF    256
#define LL    16

typedef float f32x4 __attribute__((ext_vector_type(4)));
typedef short s16x8 __attribute__((ext_vector_type(8)));

static __device__ __forceinline__ unsigned short f2bf(float f) {
    return __builtin_bit_cast(unsigned short, __float2bfloat16(f));
}
static __device__ __forceinline__ float bf2f(unsigned short u) {
    unsigned int x = ((unsigned int)u) << 16;
    return __builtin_bit_cast(float, x);
}

typedef const __attribute__((address_space(1))) unsigned int glb_uint;
typedef __attribute__((address_space(3))) unsigned int lds_uint;
static __device__ __forceinline__ void gload_lds16(const void* g, void* l) {
    __builtin_amdgcn_global_load_lds((glb_uint*)g, (lds_uint*)l, 16, 0, 0);
}

// ---------------------------------------------------------------------------
// Kernel A (fused): per 64-row tile:
//   - stage x tile as bf16 in LDS
//   - z = bf16(x) @ bf16(proj_w)^T + proj_b   (MFMA, K=256)
//   - write z bf16 + sq = |z|^2 (f32, from the SAME bf16 z -> exact diagonal)
//   - pi = sigmoid(w2 . relu(W1 @ z + b1) + b2)  (MFMA, K=16 zero-padded)
//   - xT[b][f][n] = bf16(x)   (transpose write, coalesced per f-row)
// Grid: 8*32 = 256 blocks, 256 threads (4 waves; wave wv owns rows wv*16..+16)
// ---------------------------------------------------------------------------
__global__ __launch_bounds__(256) void fused_a_kernel(
    const float* __restrict__ x,
    const float* __restrict__ proj_w, const float* __restrict__ proj_b,
    const float* __restrict__ pi_w1,  const float* __restrict__ pi_b1,
    const float* __restrict__ pi_w2,  const float* __restrict__ pi_b2,
    unsigned short* __restrict__ xT,
    unsigned short* __restrict__ zbG,
    float* __restrict__ sqbuf,
    float* __restrict__ pibuf)
{
    const int bid = blockIdx.x;
    const int b = bid & 7, nt = bid >> 3;
    const int n0 = nt * 64;
    const int t = threadIdx.x;
    const int wv = t >> 6, ln = t & 63;

    const float* xb = x + (size_t)b * NN * FF;
    unsigned short* xTb = xT + (size_t)b * FF * NN;

    __shared__ unsigned short xbsh[64 * 264];   // bf16 x tile, padded rows (528B)
    __shared__ unsigned short Wbsh[16 * 264];   // proj_w bf16 [l][f]
    __shared__ unsigned short W1bsh[256 * 24];  // pi_w1 bf16 [f][l], 48B rows
    __shared__ unsigned short zbsh[64 * 24];    // z bf16 [n][l]
    __shared__ float b1sh[256], w2sh[256], pbsh[16];

    // ---- stage x tile (f32 -> bf16) ----
#pragma unroll
    for (int i = 0; i < 16; ++i) {
        const int idx = i * 256 + t;
        const int r = idx >> 6, cq = idx & 63;
        const float4 v = *(const float4*)(xb + (size_t)(n0 + r) * FF + cq * 4);
        ushort4 o; o.x = f2bf(v.x); o.y = f2bf(v.y); o.z = f2bf(v.z); o.w = f2bf(v.w);
        *(ushort4*)&xbsh[r * 264 + cq * 4] = o;
    }
    // ---- stage weights ----
    {
        const int l = t >> 4, fq = t & 15;
#pragma unroll
        for (int k2 = 0; k2 < 4; ++k2) {
            const float4 v = *(const float4*)(proj_w + l * FF + fq * 16 + k2 * 4);
            ushort4 o; o.x = f2bf(v.x); o.y = f2bf(v.y); o.z = f2bf(v.z); o.w = f2bf(v.w);
            *(ushort4*)&Wbsh[l * 264 + fq * 16 + k2 * 4] = o;
        }
    }
    {
#pragma unroll
        for (int k2 = 0; k2 < 4; ++k2) {
            const float4 v = *(const float4*)(pi_w1 + t * LL + k2 * 4);
            ushort4 o; o.x = f2bf(v.x); o.y = f2bf(v.y); o.z = f2bf(v.z); o.w = f2bf(v.w);
            *(ushort4*)&W1bsh[t * 24 + k2 * 4] = o;
        }
        b1sh[t] = pi_b1[t];
        w2sh[t] = pi_w2[t];
        if (t < 16) pbsh[t] = proj_b[t];
    }
    __syncthreads();

    // ---- proj MFMA: rows wv*16..+16, K = 256 over 8 groups of 32 ----
    f32x4 zacc = {0.f, 0.f, 0.f, 0.f};
#pragma unroll
    for (int g = 0; g < 8; ++g) {
        const s16x8 af = *(const s16x8*)&xbsh[(wv * 16 + (ln & 15)) * 264 + g * 32 + (ln >> 4) * 8];
        const s16x8 bf = *(const s16x8*)&Wbsh[(ln & 15) * 264 + g * 32 + (ln >> 4) * 8];
        zacc = __builtin_amdgcn_mfma_f32_16x16x32_bf16(af, bf, zacc, 0, 0, 0);
    }
    {
        const float pb = pbsh[ln & 15];
#pragma unroll
        for (int r = 0; r < 4; ++r) {
            const float zv = zacc[r] + pb;
            zbsh[(wv * 16 + (ln >> 4) * 4 + r) * 24 + (ln & 15)] = f2bf(zv);
        }
    }
    __syncthreads();

    // ---- z bf16 -> global, sq from bf16 z ----
    if (t < 64) {
        unsigned short zr[16];
        float sq = 0.f;
#pragma unroll
        for (int l = 0; l < 16; ++l) {
            zr[l] = zbsh[t * 24 + l];
            const float zf = bf2f(zr[l]);
            sq = fmaf(zf, zf, sq);
        }
        const size_t gz = ((size_t)b * NN + n0 + t) * 16;
#pragma unroll
        for (int q4 = 0; q4 < 4; ++q4)
            *(ushort4*)(zbG + gz + q4 * 4) = *(ushort4*)&zr[q4 * 4];
        sqbuf[(size_t)b * NN + n0 + t] = sq;
    }

    // ---- MLP via MFMA (A = W1 rows f, B = z rows n; K = 16, upper 16 zero) ----
    {
        s16x8 bz = {0, 0, 0, 0, 0, 0, 0, 0};
        if ((ln >> 4) < 2)
            bz = *(const s16x8*)&zbsh[(wv * 16 + (ln & 15)) * 24 + (ln >> 4) * 8];
        float pisum = 0.f;
        const f32x4 zf4 = {0.f, 0.f, 0.f, 0.f};
#pragma unroll
        for (int ft = 0; ft < 16; ++ft) {
            s16x8 aw = {0, 0, 0, 0, 0, 0, 0, 0};
            if ((ln >> 4) < 2)
                aw = *(const s16x8*)&W1bsh[(ft * 16 + (ln & 15)) * 24 + (ln >> 4) * 8];
            const f32x4 h4 = __builtin_amdgcn_mfma_f32_16x16x32_bf16(aw, bz, zf4, 0, 0, 0);
#pragma unroll
            for (int r = 0; r < 4; ++r) {
                const int f = ft * 16 + (ln >> 4) * 4 + r;
                float h = h4[r] + b1sh[f];
                h = fmaxf(h, 0.f);
                pisum = fmaf(h, w2sh[f], pisum);
            }
        }
        pisum += __shfl_xor(pisum, 16, 64);
        pisum += __shfl_xor(pisum, 32, 64);
        if (ln < 16) {
            const float tp = pisum + pi_b2[0];
            pibuf[(size_t)b * NN + n0 + wv * 16 + ln] = 1.f / (1.f + __expf(-tp));
        }
    }

    // ---- transpose write: wave wv covers f = wv*64..+64; lane = n ----
    {
        const int foff = wv * 64;
#pragma unroll
        for (int ff = 0; ff < 64; ++ff) {
            const unsigned short v = xbsh[ln * 264 + foff + ff];
            xTb[(size_t)(foff + ff) * NN + n0 + ln] = v;
        }
    }
}

// ---------------------------------------------------------------------------
// Kernel Q: q[n] = sum_m exp(2 z_n.z_m - sq_n - sq_m) via gram MFMA;
// c[n] = pi[n]/q[n].  64 rows/block, 256 thr (4 waves, ntile per wave).
// m chunked by 256, double-buffered LDS with register prefetch.
// ---------------------------------------------------------------------------
__global__ __launch_bounds__(256) void qc_kernel(
    const unsigned short* __restrict__ zbG,
    const float* __restrict__ sqbuf,
    const float* __restrict__ pibuf,
    float* __restrict__ cbuf)
{
    const int bid = blockIdx.x;
    const int b = bid & 7, nt = bid >> 3;
    const int n0 = nt * 64;
    const int t = threadIdx.x;
    const int wv = t >> 6, ln = t & 63;

    const unsigned short* zb = zbG + (size_t)b * NN * LL;
    const float* sqb = sqbuf + (size_t)b * NN;

    __shared__ unsigned short zq[2][256 * 24];
    __shared__ float sqq[2][256];

    s16x8 af = {0, 0, 0, 0, 0, 0, 0, 0};
    if ((ln >> 4) < 2)
        af = *(const s16x8*)(zb + (size_t)(n0 + wv * 16 + (ln & 15)) * 16 + (ln >> 4) * 8);
    float sqn[4];
#pragma unroll
    for (int r = 0; r < 4; ++r) sqn[r] = sqb[n0 + wv * 16 + (ln >> 4) * 4 + r];

    float S[4] = {0.f, 0.f, 0.f, 0.f};
    const f32x4 zf4 = {0.f, 0.f, 0.f, 0.f};

    uint4 za, zc; float sv;
    // prologue: stage chunk 0
    za = *(const uint4*)(zb + (size_t)t * 16);
    zc = *(const uint4*)(zb + (size_t)t * 16 + 8);
    sv = sqb[t];
    *(uint4*)&zq[0][t * 24] = za;
    *(uint4*)&zq[0][t * 24 + 8] = zc;
    sqq[0][t] = sv;
    __syncthreads();

    for (int ch = 0; ch < 8; ++ch) {
        const int cur = ch & 1;
        if (ch < 7) {
            const int m = (ch + 1) * 256 + t;
            za = *(const uint4*)(zb + (size_t)m * 16);
            zc = *(const uint4*)(zb + (size_t)m * 16 + 8);
            sv = sqb[m];
        }
#pragma unroll
        for (int mt = 0; mt < 16; ++mt) {
            const int mloc = mt * 16 + (ln & 15);
            s16x8 bf = {0, 0, 0, 0, 0, 0, 0, 0};
            if ((ln >> 4) < 2)
                bf = *(const s16x8*)&zq[cur][mloc * 24 + (ln >> 4) * 8];
            const f32x4 g = __builtin_amdgcn_mfma_f32_16x16x32_bf16(af, bf, zf4, 0, 0, 0);
            const float sqm = sqq[cur][mloc];
#pragma unroll
            for (int r = 0; r < 4; ++r)
                S[r] += __expf(2.f * g[r] - sqn[r] - sqm);
        }
        if (ch < 7) {
            *(uint4*)&zq[cur ^ 1][t * 24] = za;
            *(uint4*)&zq[cur ^ 1][t * 24 + 8] = zc;
            sqq[cur ^ 1][t] = sv;
        }
        __syncthreads();
    }
#pragma unroll
    for (int r = 0; r < 4; ++r) {
        S[r] += __shfl_xor(S[r], 1, 64);
        S[r] += __shfl_xor(S[r], 2, 64);
        S[r] += __shfl_xor(S[r], 4, 64);
        S[r] += __shfl_xor(S[r], 8, 64);
    }
    if ((ln & 15) == 0) {
#pragma unroll
        for (int r = 0; r < 4; ++r) {
            const int n = n0 + wv * 16 + (ln >> 4) * 4 + r;
            const size_t gi = (size_t)b * NN + n;
            cbuf[gi] = pibuf[gi] / S[r];
        }
    }
}

// ---------------------------------------------------------------------------
// Kernel M: out[n,f] = (1-dt)x[n,f] + 4dt/(rowsum+1e-5) * sum_m w[n,m] x[m,f]
//   w[n,m] = exp(2 z_n.z_m - sq_n - sq_m) * c[m]   (gram via MFMA)
// Tile 64n x 256f, 512 thr (8 waves). Per 64-m chunk:
//   phase1: gram MFMA (wave -> (ntile=wv>>1, 2 mtiles)) + exp + c -> wsh bf16
//   phase2: 16x mfma_16x16x32 per wave (wave f-slab = 32 cols)
// xsh: wave-local slabs staged via global_load_lds, double-buffered; issue is
// right AFTER the barrier so the next barrier's vmcnt(0) drain is overlapped
// by phase2 + next phase1.  ONE __syncthreads per chunk.
// Grid: 8*32 = 256 (1 block/CU), batch = bid&7 -> XCD L2 locality.
// ---------------------------------------------------------------------------
__global__ __launch_bounds__(512) void main_kernel(
    const float* __restrict__ x,
    const unsigned short* __restrict__ xT,
    const unsigned short* __restrict__ zbG,
    const float* __restrict__ sqbuf,
    const float* __restrict__ cbuf,
    const float* __restrict__ dtp,
    float* __restrict__ out)
{
    const int bid = blockIdx.x;
    const int b = bid & 7, nt = bid >> 3;
    const int n0 = nt * 64;
    const int t = threadIdx.x;
    const int wv = t >> 6, ln = t & 63;

    const float*          xb  = x   + (size_t)b * NN * FF;
    const unsigned short* xTb = xT  + (size_t)b * FF * NN;
    const unsigned short* zb  = zbG + (size_t)b * NN * LL;
    const float*          sqB = sqbuf + (size_t)b * NN;
    const float*          cB  = cbuf  + (size_t)b * NN;
    float*                ob  = out + (size_t)b * NN * FF;

    __shared__ unsigned short xsh[2 * 16384];  // 64KB: [buf][wave slab 4KB][32f][64m]
    __shared__ unsigned short wsh[2 * 4096];   // 16KB: [buf][64n][64m] bf16
    __shared__ unsigned short zsh[2 * 64 * 24];// 6KB bf16 z chunk
    __shared__ float csh[2][64], sqh[2][64];
    __shared__ float rsp[2][64];

    const float dtv = dtp[0];
    const int ntile = wv >> 1;

    // phase-1 A-frag (z_n rows of this wave's ntile), fixed across chunks
    s16x8 af = {0, 0, 0, 0, 0, 0, 0, 0};
    if ((ln >> 4) < 2)
        af = *(const s16x8*)(zb + (size_t)(n0 + ntile * 16 + (ln & 15)) * 16 + (ln >> 4) * 8);
    float sqn[4];
#pragma unroll
    for (int r = 0; r < 4; ++r) sqn[r] = sqB[n0 + ntile * 16 + (ln >> 4) * 4 + r];

    f32x4 acc[2][4];
#pragma unroll
    for (int fi = 0; fi < 2; ++fi)
#pragma unroll
        for (int ni = 0; ni < 4; ++ni) acc[fi][ni] = (f32x4){0.f, 0.f, 0.f, 0.f};
    float rloc[4] = {0.f, 0.f, 0.f, 0.f};
    const f32x4 zf4 = {0.f, 0.f, 0.f, 0.f};

    uint4 zreg; float creg = 0.f, sreg = 0.f;

    // ---------------- prologue: stage chunk 0 ----------------
    if (t < 128) {
        const int m = t >> 1, half = t & 1;
        zreg = *(const uint4*)(zb + (size_t)m * 16 + half * 8);
        *(uint4*)&zsh[m * 24 + half * 8] = zreg;
    } else if (t < 192) {
        csh[0][t - 128] = cB[t - 128];
    } else if (t < 256) {
        sqh[0][t - 192] = sqB[t - 192];
    }
#pragma unroll
    for (int i = 0; i < 4; ++i) {
        const int floc = i * 8 + (ln >> 3);
        const int cp = ln & 7;
        const int cl = cp ^ (floc & 7);
        const unsigned short* src = xTb + (size_t)(wv * 32 + floc) * NN + cl * 8;
        gload_lds16(src, (char*)xsh + wv * 4096 + i * 1024);
    }
    __syncthreads();

    for (int kt = 0; kt < 32; ++kt) {
        const int cur = kt & 1;
        unsigned short* zc = zsh + cur * (64 * 24);
        unsigned short* wc = wsh + cur * 4096;
        const unsigned short* xc = xsh + cur * 16384;

        // prefetch next z/c/sq chunk into registers
        if (kt < 31) {
            const int m1 = (kt + 1) * 64;
            if (t < 128) {
                const int m = t >> 1, half = t & 1;
                zreg = *(const uint4*)(zb + (size_t)(m1 + m) * 16 + half * 8);
            } else if (t < 192) creg = cB[m1 + t - 128];
            else if (t < 256)   sreg = sqB[m1 + t - 192];
        }

        // ---- phase 1: w tile via gram MFMA ----
#pragma unroll
        for (int mi = 0; mi < 2; ++mi) {
            const int mt = (wv & 1) * 2 + mi;
            const int mloc = mt * 16 + (ln & 15);
            s16x8 bf = {0, 0, 0, 0, 0, 0, 0, 0};
            if ((ln >> 4) < 2)
                bf = *(const s16x8*)&zc[mloc * 24 + (ln >> 4) * 8];
            const f32x4 g = __builtin_amdgcn_mfma_f32_16x16x32_bf16(af, bf, zf4, 0, 0, 0);
            const float sqm = sqh[cur][mloc], cm = csh[cur][mloc];
#pragma unroll
            for (int r = 0; r < 4; ++r) {
                const float e = 2.f * g[r] - sqn[r] - sqm;
                const float wf = __expf(e) * cm;
                rloc[r] += wf;
                const int nr = ntile * 16 + (ln >> 4) * 4 + r;
                const int phys = (mloc >> 3) ^ (nr & 7);
                wc[nr * 64 + phys * 8 + (mloc & 7)] = f2bf(wf);
            }
        }

        // write prefetched z/c/sq into the other buffer
        if (kt < 31) {
            unsigned short* zn = zsh + (cur ^ 1) * (64 * 24);
            if (t < 128) {
                const int m = t >> 1, half = t & 1;
                *(uint4*)&zn[m * 24 + half * 8] = zreg;
            } else if (t < 192) csh[cur ^ 1][t - 128] = creg;
            else if (t < 256)   sqh[cur ^ 1][t - 192] = sreg;
        }
        __syncthreads();   // drains: xsh[cur] loads issued last iteration (overlapped)

        // issue next xsh chunk (wave-local slab) -> drained at NEXT barrier
        if (kt < 31) {
            const int m1 = (kt + 1) * 64;
            char* xn = (char*)xsh + (cur ^ 1) * 32768;
#pragma unroll
            for (int i = 0; i < 4; ++i) {
                const int floc = i * 8 + (ln >> 3);
                const int cp = ln & 7;
                const int cl = cp ^ (floc & 7);
                const unsigned short* src = xTb + (size_t)(wv * 32 + floc) * NN + m1 + cl * 8;
                gload_lds16(src, xn + wv * 4096 + i * 1024);
            }
        }
        __builtin_amdgcn_sched_barrier(0);

        // ---- phase 2: 16 MFMA per wave ----
#pragma unroll
        for (int ks = 0; ks < 2; ++ks) {
            s16x8 a2[2], bw[4];
#pragma unroll
            for (int fi = 0; fi < 2; ++fi) {
                const int floc = fi * 16 + (ln & 15);
                const int phys = (ks * 4 + (ln >> 4)) ^ (floc & 7);
                a2[fi] = *(const s16x8*)&xc[wv * 2048 + floc * 64 + phys * 8];
            }
#pragma unroll
            for (int ni = 0; ni < 4; ++ni) {
                const int nr2 = ni * 16 + (ln & 15);
                const int phys = (ks * 4 + (ln >> 4)) ^ (nr2 & 7);
                bw[ni] = *(const s16x8*)&wc[nr2 * 64 + phys * 8];
            }
#pragma unroll
            for (int fi = 0; fi < 2; ++fi)
#pragma unroll
                for (int ni = 0; ni < 4; ++ni)
                    acc[fi][ni] = __builtin_amdgcn_mfma_f32_16x16x32_bf16(
                        a2[fi], bw[ni], acc[fi][ni], 0, 0, 0);
        }
    }

    // ---- rowsum: reduce over 16 column-lanes, combine the two mtile-halves ----
#pragma unroll
    for (int r = 0; r < 4; ++r) {
        rloc[r] += __shfl_xor(rloc[r], 1, 64);
        rloc[r] += __shfl_xor(rloc[r], 2, 64);
        rloc[r] += __shfl_xor(rloc[r], 4, 64);
        rloc[r] += __shfl_xor(rloc[r], 8, 64);
    }
    if ((ln & 15) == 0) {
#pragma unroll
        for (int r = 0; r < 4; ++r)
            rsp[wv & 1][ntile * 16 + (ln >> 4) * 4 + r] = rloc[r];
    }
    __syncthreads();

    // ---- epilogue ----
#pragma unroll
    for (int ni = 0; ni < 4; ++ni) {
        const int nr = ni * 16 + (ln & 15);
        const float rstot = rsp[0][nr] + rsp[1][nr] + 1e-5f;
        const float sc = 4.f * dtv / rstot;
        const int ng = n0 + nr;
#pragma unroll
        for (int fi = 0; fi < 2; ++fi) {
            const int fg = wv * 32 + fi * 16 + (ln >> 4) * 4;
            const float4 xv = *(const float4*)(xb + (size_t)ng * FF + fg);
            float4 o;
            o.x = (1.f - dtv) * xv.x + sc * acc[fi][ni][0];
            o.y = (1.f - dtv) * xv.y + sc * acc[fi][ni][1];
            o.z = (1.f - dtv) * xv.z + sc * acc[fi][ni][2];
            o.w = (1.f - dtv) * xv.w + sc * acc[fi][ni][3];
            *(float4*)(ob + (size_t)ng * FF + fg) = o;
        }
    }
}

// ---------------------------------------------------------------------------
extern "C" void kernel_launch(void* const* d_in, const int* in_sizes, int n_in,
                              void* d_out, int out_size, void* d_ws, size_t ws_size,
                              hipStream_t stream) {
    const float* x      = (const float*)d_in[0];
    const float* proj_w = (const float*)d_in[1];
    const float* proj_b = (const float*)d_in[2];
    const float* pi_w1  = (const float*)d_in[3];
    const float* pi_b1  = (const float*)d_in[4];
    const float* pi_w2  = (const float*)d_in[5];
    const float* pi_b2  = (const float*)d_in[6];
    const float* dtp    = (const float*)d_in[7];
    float* out = (float*)d_out;

    // workspace: xT bf16 8MB | z bf16 512KB | sq 64KB | pi 64KB | c 64KB
    unsigned short* xT  = (unsigned short*)d_ws;
    unsigned short* zbG = xT + (size_t)BATCH * FF * NN;
    float* sqbuf = (float*)(zbG + (size_t)BATCH * NN * LL);
    float* pibuf = sqbuf + (size_t)BATCH * NN;
    float* cbuf  = pibuf + (size_t)BATCH * NN;

    fused_a_kernel<<<dim3(BATCH * (NN / 64)), dim3(256), 0, stream>>>(
        x, proj_w, proj_b, pi_w1, pi_b1, pi_w2, pi_b2, xT, zbG, sqbuf, pibuf);

    qc_kernel<<<dim3(BATCH * (NN / 64)), dim3(256), 0, stream>>>(
        zbG, sqbuf, pibuf, cbuf);

    main_kernel<<<dim3(BATCH * (NN / 64)), dim3(512), 0, stream>>>(
        x, xT, zbG, sqbuf, cbuf, dtp, out);
}